// Round 13
// baseline (32.169 us; speedup 1.0000x reference)
//
#include <hip/hip_runtime.h>
#include <hip/hip_bf16.h>
#include <math.h>

// Sizes: B=512, IN=512, D=64, L=256, WF=0.5
//
// Reduction (verified): output only uses mem_new[:L] = w[0, 0:256, :], so the
// write path collapses to a (256,256) coefficient matrix c[i,l], and
//   out[b] = sigmoid( sum_{i,l} c[i,l] * softmax_l(lf[b,:]@kernel_r[i,:,:])[l] )
// Three kernels:
//   k_front: l1 + heads, one block per batch row (r12-verified).
//   k_mainc: grid 512 = (i, l-half): 2 blocks/CU for latency overlap.
//            Coalesced prefetch-all staging of the 128-col half (16 KB LDS,
//            XOR-swizzled reads conflict-free), c-phase (full 256-l denom),
//            MFMA einsum, partial softmax sums (se,sw) per half.
//   k_out2:  combine halves, divide, reduce over i, sigmoid (r5-verified).
// NOTE: ticket/fence last-block patterns cost ~40us on this chip (r6/r9/r11)
// -> never again.

typedef __attribute__((ext_vector_type(8))) short short8;
typedef __attribute__((ext_vector_type(4))) float f32x4;
typedef __attribute__((ext_vector_type(2))) float f32x2;

static __device__ __forceinline__ unsigned short f2bf(float f) {
    __hip_bfloat16 h = __float2bfloat16(f);
    return *reinterpret_cast<unsigned short*>(&h);
}

// Fused front-end, one block per batch row b (grid 512, 256 threads).
__global__ __launch_bounds__(256) void k_front(
    const float* __restrict__ x,
    const float* __restrict__ k1,  const float* __restrict__ b1,
    const float* __restrict__ k20, const float* __restrict__ b20,
    const float* __restrict__ k2,  const float* __restrict__ b2,
    const float* __restrict__ k30, const float* __restrict__ b30,
    const float* __restrict__ k3,  const float* __restrict__ b3,
    const float* __restrict__ k40, const float* __restrict__ b40,
    const float* __restrict__ k4,  const float* __restrict__ b4,
    unsigned short* __restrict__ lf_bf,  // (512,64) bf16
    float* __restrict__ lfw,             // (256,64)
    float* __restrict__ lbw0) {          // (256)
    __shared__ float xs[512];
    __shared__ float part[4][64];
    __shared__ float l1s[60];
    __shared__ float hid2[50], hid3[50], hid4[50];
    const int b = blockIdx.x, t = threadIdx.x;
    const int c = t & 63, kq = t >> 6;

    {
        const float2 xv = *(const float2*)&x[b * 512 + t * 2];
        xs[t * 2] = xv.x;
        xs[t * 2 + 1] = xv.y;
    }
    __syncthreads();

    // phase 1: 4-way K-split x 4 independent accumulators
    {
        float a0 = 0.f, a1 = 0.f, a2 = 0.f, a3 = 0.f;
        if (c < 60) {
            const float* xk = xs + kq * 128;
            const float* kp = k1 + (kq * 128) * 60 + c;
#pragma unroll 4
            for (int k = 0; k < 128; k += 4) {
                a0 += xk[k + 0] * kp[(k + 0) * 60];
                a1 += xk[k + 1] * kp[(k + 1) * 60];
                a2 += xk[k + 2] * kp[(k + 2) * 60];
                a3 += xk[k + 3] * kp[(k + 3) * 60];
            }
        }
        part[kq][c] = (a0 + a1) + (a2 + a3);
    }
    __syncthreads();
    if (t < 60)
        l1s[t] = fmaxf(b1[t] + part[0][t] + part[1][t] + part[2][t] + part[3][t], 0.f);
    __syncthreads();

    // phase 2: hidden layers (60 -> 50), one wave each
    if (t < 50) {
        float a = b20[t];
#pragma unroll
        for (int k = 0; k < 60; ++k) a += l1s[k] * k20[k * 50 + t];
        hid2[t] = fmaxf(a, 0.f);
    } else if (t >= 64 && t < 114 && b < 256) {
        const int j = t - 64;
        float a = b30[j];
#pragma unroll
        for (int k = 0; k < 60; ++k) a += l1s[k] * k30[k * 50 + j];
        hid3[j] = fmaxf(a, 0.f);
    } else if (t >= 128 && t < 178 && b == 0) {
        const int j = t - 128;
        float a = b40[j];
#pragma unroll
        for (int k = 0; k < 60; ++k) a += l1s[k] * k40[k * 50 + j];
        hid4[j] = fmaxf(a, 0.f);
    }
    __syncthreads();

    // phase 3: heads (50 -> 64), one wave each
    if (t < 64) {
        float a = b2[t];
#pragma unroll
        for (int k = 0; k < 50; ++k) a += hid2[k] * k2[k * 64 + t];
        lf_bf[b * 64 + t] = f2bf(fmaxf(a, 0.f));
    } else if (t < 128 && b < 256) {
        const int j = t - 64;
        float a = b3[j];
#pragma unroll
        for (int k = 0; k < 50; ++k) a += hid3[k] * k3[k * 64 + j];
        lfw[b * 64 + j] = fmaxf(a, 0.f);
    }
    if (b == 0) {
        __syncthreads();
        float a = b4[t];
#pragma unroll
        for (int k = 0; k < 50; ++k) a += hid4[k] * k4[k * 256 + t];
        lbw0[t] = tanhf(a);
    }
}

// c-coefficients + MFMA einsum + partial softmax sums.
// Grid 512: block (i = blk>>1, h = blk&1) covers l in [h*128, h*128+128) for
// ALL 512 batch rows. 512 threads = 8 waves; launch_bounds(512,4) caps VGPR
// at 128 -> 2 blocks/CU co-resident (the latency-overlap lever).
__global__ __launch_bounds__(512, 4) void k_mainc(
    const unsigned short* __restrict__ lf,   // (512,64) bf16 bits
    const float* __restrict__ kernel_r,      // (256,64,256) f32
    const float* __restrict__ lfw,           // (256,64)
    const float* __restrict__ kw,            // (256,64,256), j=0 slice
    const float* __restrict__ mem,           // row 0 used
    const float* __restrict__ lbw0,          // (256)
    const float* __restrict__ wsig,          // (65536)
    float* __restrict__ partial) {           // (512,256,4): se0,sw0,se1,sw1
    __shared__ __align__(16) unsigned short KrT[128 * 64];  // 16 KB
    __shared__ float cLDS[128];
    __shared__ float wpart[4];
    const int i = blockIdx.x >> 1;
    const int h = blockIdx.x & 1;
    const int tid = threadIdx.x;
    const int lane = tid & 63;
    const int wv = tid >> 6;

    // Stage half-tile: COALESCED (wave-uniform d, 64 consecutive l = 256 B
    // per load) + PREFETCH-ALL (16 loads in flight before converting).
    // XOR swizzle (byte ^= (l&7)<<4) keeps ds_read_b128 conflict-free;
    // ds_write takes a benign 8-way conflict. (r10/r12-verified pattern)
    {
        const int l = tid & 127;           // local l within half
        const int dh = tid >> 7;           // 0..3, 16 d's each
        const float* src = kernel_r + (size_t)i * 16384 + (size_t)dh * 16 * 256
                         + h * 128 + l;
        float v[16];
#pragma unroll
        for (int j = 0; j < 16; ++j) v[j] = src[(size_t)j * 256];
        char* lds = (char*)KrT;
#pragma unroll
        for (int j = 0; j < 8; ++j) {
            const int d = dh * 16 + 2 * j;
            const unsigned int pk =
                (unsigned int)f2bf(v[2 * j]) | ((unsigned int)f2bf(v[2 * j + 1]) << 16);
            const int byteoff = ((l * 64 + d) * 2) ^ ((l & 7) << 4);
            *(unsigned int*)(lds + byteoff) = pk;
        }
    }

    // c-phase (threads 0..255, one GLOBAL l each; full 256-l softmax
    // denominator). 4 independent accumulators; logits O(0.04) -> no max-sub.
    float e_c = 0.f;
    if (tid < 256) {
        const int l = tid;
        float s0 = 0.f, s1 = 0.f, s2 = 0.f, s3 = 0.f;
        const float* lrow = lfw + i * 64;
        const float* kp = kw + l;
#pragma unroll 4
        for (int d = 0; d < 64; d += 4) {
            s0 += lrow[d + 0] * kp[(d + 0) * 256];
            s1 += lrow[d + 1] * kp[(d + 1) * 256];
            s2 += lrow[d + 2] * kp[(d + 2) * 256];
            s3 += lrow[d + 3] * kp[(d + 3) * 256];
        }
        e_c = __expf((s0 + s1) + (s2 + s3));
        float se = e_c;
#pragma unroll
        for (int off = 1; off < 64; off <<= 1) se += __shfl_xor(se, off, 64);
        if (lane == 0) wpart[wv] = se;
    }
    __syncthreads();
    if (tid < 256 && (tid >> 7) == h) {
        const int l = tid;
        const float tot = wpart[0] + wpart[1] + wpart[2] + wpart[3];
        cLDS[l & 127] = mem[l] * (e_c / tot) * (1.f + 0.5f * lbw0[l]) * wsig[i * 256 + l];
    }
    __syncthreads();

    const int c = lane & 15, g = lane >> 4;

    // B fragments: 8 N-tiles x 2 K-halves (16 short8 = 64 VGPR).
    short8 Bf0[8], Bf1[8];
    {
        const char* lds = (const char*)KrT;
#pragma unroll
        for (int n = 0; n < 8; ++n) {
            const int l = n * 16 + c;
            const int base = l * 128 + g * 16;
            Bf0[n] = *(const short8*)(lds + ((base) ^ ((l & 7) << 4)));
            Bf1[n] = *(const short8*)(lds + ((base + 64) ^ ((l & 7) << 4)));
        }
    }
    float ccv[8];
#pragma unroll
    for (int n = 0; n < 8; ++n) ccv[n] = cLDS[n * 16 + c];

#pragma unroll
    for (int p = 0; p < 4; ++p) {
        const int b0 = wv * 64 + p * 16;
        const short8 a0 = *(const short8*)(lf + (b0 + c) * 64 + g * 8);
        const short8 a1 = *(const short8*)(lf + (b0 + c) * 64 + 32 + g * 8);
        f32x4 acc[8];
#pragma unroll
        for (int n = 0; n < 8; ++n) acc[n] = (f32x4){0.f, 0.f, 0.f, 0.f};
#pragma unroll
        for (int n = 0; n < 8; ++n) {
            acc[n] = __builtin_amdgcn_mfma_f32_16x16x32_bf16(a0, Bf0[n], acc[n], 0, 0, 0);
            acc[n] = __builtin_amdgcn_mfma_f32_16x16x32_bf16(a1, Bf1[n], acc[n], 0, 0, 0);
        }
        // D layout: row = (lane>>4)*4 + r, col(local) = n*16 + (lane&15).
        // Partial softmax sums over this half's 128 cols.
#pragma unroll
        for (int r = 0; r < 4; ++r) {
            float se = 0.f, sw = 0.f;
#pragma unroll
            for (int n = 0; n < 8; ++n) {
                const float e = __expf(acc[n][r]);
                se += e;
                sw += ccv[n] * e;
            }
#pragma unroll
            for (int off = 1; off < 16; off <<= 1) {
                se += __shfl_xor(se, off, 64);
                sw += __shfl_xor(sw, off, 64);
            }
            if (c == 0) {
                const int b = b0 + g * 4 + r;
                *(f32x2*)&partial[((size_t)b * 256 + i) * 4 + h * 2] =
                    (f32x2){se, sw};
            }
        }
    }
}

// Combine halves, divide, reduce over i, sigmoid. 8 rows per block.
__global__ __launch_bounds__(256) void k_out2(const float* __restrict__ partial,
                                              float* __restrict__ out) {
    const int t = threadIdx.x;
    const int rq = t >> 6, lane = t & 63;
#pragma unroll
    for (int p = 0; p < 2; ++p) {
        const int row = blockIdx.x * 8 + p * 4 + rq;
        float s = 0.f;
#pragma unroll
        for (int q = 0; q < 4; ++q) {
            const int i = q * 64 + lane;
            const f32x4 v = *(const f32x4*)&partial[((size_t)row * 256 + i) * 4];
            s += (v.y + v.w) / (v.x + v.z);
        }
#pragma unroll
        for (int off = 1; off < 64; off <<= 1) s += __shfl_xor(s, off, 64);
        if (lane == 0) out[row] = 1.f / (1.f + __expf(-s));
    }
}

extern "C" void kernel_launch(void* const* d_in, const int* in_sizes, int n_in,
                              void* d_out, int out_size, void* d_ws, size_t ws_size,
                              hipStream_t stream) {
    (void)in_sizes; (void)n_in; (void)out_size; (void)ws_size;
    const float* x    = (const float*)d_in[0];
    const float* mem  = (const float*)d_in[1];
    const float* k1   = (const float*)d_in[2];
    const float* b1   = (const float*)d_in[3];
    const float* k20  = (const float*)d_in[4];
    const float* b20  = (const float*)d_in[5];
    const float* k30  = (const float*)d_in[6];
    const float* b30  = (const float*)d_in[7];
    const float* k40  = (const float*)d_in[8];
    const float* b40  = (const float*)d_in[9];
    const float* k2   = (const float*)d_in[10];
    const float* b2   = (const float*)d_in[11];
    const float* k3   = (const float*)d_in[12];
    const float* b3   = (const float*)d_in[13];
    const float* k4   = (const float*)d_in[14];
    const float* b4   = (const float*)d_in[15];
    const float* kr   = (const float*)d_in[16];
    const float* kw   = (const float*)d_in[17];
    const float* wsig = (const float*)d_in[18];
    float* out = (float*)d_out;

    float* ws   = (float*)d_ws;
    float* lfw  = ws;                    // 256*64 f
    float* lbw0 = lfw + 256 * 64;        // 256 f
    float* part = lbw0 + 256;            // 512*256*4 f (2 MB)
    unsigned short* lf_bf = (unsigned short*)(part + 524288);  // 512*64 bf16

    hipLaunchKernelGGL(k_front, dim3(512), dim3(256), 0, stream, x,
                       k1, b1, k20, b20, k2, b2, k30, b30, k3, b3,
                       k40, b40, k4, b4, lf_bf, lfw, lbw0);
    hipLaunchKernelGGL(k_mainc, dim3(512), dim3(512), 0, stream,
                       lf_bf, kr, lfw, kw, mem, lbw0, wsig, part);
    hipLaunchKernelGGL(k_out2,  dim3(64),  dim3(256), 0, stream, part, out);
}

// Round 14
// 28.402 us; speedup vs baseline: 1.1326x; 1.1326x over previous
//
#include <hip/hip_runtime.h>
#include <hip/hip_bf16.h>
#include <math.h>

// Sizes: B=512, IN=512, D=64, L=256, WF=0.5
//
// Reduction (verified): output only uses mem_new[:L] = w[0, 0:256, :], so the
// write path collapses to a (256,256) coefficient matrix c[i,l], and
//   out[b] = sigmoid( sum_{i,l} c[i,l] * softmax_l(lf[b,:]@kernel_r[i,:,:])[l] )
// Three kernels (r12 structure = best verified 29.9 us):
//   k_front: l1 + heads, one block per batch row. r14: 8-way ILP in phase 1.
//   k_mainc: c + MFMA einsum + fused softmax + partial store, one block per i,
//            grid 256, launch_bounds(512,1). r14: A-fragments hoisted.
//   k_out2:  reduce over i + sigmoid. r14: grid 128 (4 rows/block).
// NOTES: ticket/fence patterns cost ~40us (r6/r9/r11) -> never. N-half split
// regresses (r5/r13): co-resident blocks phase-lock. Staging must be
// coalesced (wave-uniform d) + prefetch-all (r10/r12).

typedef __attribute__((ext_vector_type(8))) short short8;
typedef __attribute__((ext_vector_type(4))) float f32x4;

static __device__ __forceinline__ unsigned short f2bf(float f) {
    __hip_bfloat16 h = __float2bfloat16(f);
    return *reinterpret_cast<unsigned short*>(&h);
}

// Fused front-end, one block per batch row b (grid 512, 256 threads).
__global__ __launch_bounds__(256) void k_front(
    const float* __restrict__ x,
    const float* __restrict__ k1,  const float* __restrict__ b1,
    const float* __restrict__ k20, const float* __restrict__ b20,
    const float* __restrict__ k2,  const float* __restrict__ b2,
    const float* __restrict__ k30, const float* __restrict__ b30,
    const float* __restrict__ k3,  const float* __restrict__ b3,
    const float* __restrict__ k40, const float* __restrict__ b40,
    const float* __restrict__ k4,  const float* __restrict__ b4,
    unsigned short* __restrict__ lf_bf,  // (512,64) bf16
    float* __restrict__ lfw,             // (256,64)
    float* __restrict__ lbw0) {          // (256)
    __shared__ float xs[512];
    __shared__ float part[4][64];
    __shared__ float l1s[60];
    __shared__ float hid2[50], hid3[50], hid4[50];
    const int b = blockIdx.x, t = threadIdx.x;
    const int c = t & 63, kq = t >> 6;

    {
        const float2 xv = *(const float2*)&x[b * 512 + t * 2];
        xs[t * 2] = xv.x;
        xs[t * 2 + 1] = xv.y;
    }
    __syncthreads();

    // phase 1: 4-way K-split x 8 independent accumulators (8 loads in flight)
    {
        float a0 = 0.f, a1 = 0.f, a2 = 0.f, a3 = 0.f;
        float a4 = 0.f, a5 = 0.f, a6 = 0.f, a7 = 0.f;
        if (c < 60) {
            const float* xk = xs + kq * 128;
            const float* kp = k1 + (kq * 128) * 60 + c;
#pragma unroll 2
            for (int k = 0; k < 128; k += 8) {
                a0 += xk[k + 0] * kp[(k + 0) * 60];
                a1 += xk[k + 1] * kp[(k + 1) * 60];
                a2 += xk[k + 2] * kp[(k + 2) * 60];
                a3 += xk[k + 3] * kp[(k + 3) * 60];
                a4 += xk[k + 4] * kp[(k + 4) * 60];
                a5 += xk[k + 5] * kp[(k + 5) * 60];
                a6 += xk[k + 6] * kp[(k + 6) * 60];
                a7 += xk[k + 7] * kp[(k + 7) * 60];
            }
        }
        part[kq][c] = ((a0 + a1) + (a2 + a3)) + ((a4 + a5) + (a6 + a7));
    }
    __syncthreads();
    if (t < 60)
        l1s[t] = fmaxf(b1[t] + part[0][t] + part[1][t] + part[2][t] + part[3][t], 0.f);
    __syncthreads();

    // phase 2: hidden layers (60 -> 50), one wave each
    if (t < 50) {
        float a = b20[t];
#pragma unroll
        for (int k = 0; k < 60; ++k) a += l1s[k] * k20[k * 50 + t];
        hid2[t] = fmaxf(a, 0.f);
    } else if (t >= 64 && t < 114 && b < 256) {
        const int j = t - 64;
        float a = b30[j];
#pragma unroll
        for (int k = 0; k < 60; ++k) a += l1s[k] * k30[k * 50 + j];
        hid3[j] = fmaxf(a, 0.f);
    } else if (t >= 128 && t < 178 && b == 0) {
        const int j = t - 128;
        float a = b40[j];
#pragma unroll
        for (int k = 0; k < 60; ++k) a += l1s[k] * k40[k * 50 + j];
        hid4[j] = fmaxf(a, 0.f);
    }
    __syncthreads();

    // phase 3: heads (50 -> 64), one wave each
    if (t < 64) {
        float a = b2[t];
#pragma unroll
        for (int k = 0; k < 50; ++k) a += hid2[k] * k2[k * 64 + t];
        lf_bf[b * 64 + t] = f2bf(fmaxf(a, 0.f));
    } else if (t < 128 && b < 256) {
        const int j = t - 64;
        float a = b3[j];
#pragma unroll
        for (int k = 0; k < 50; ++k) a += hid3[k] * k3[k * 64 + j];
        lfw[b * 64 + j] = fmaxf(a, 0.f);
    }
    if (b == 0) {
        __syncthreads();
        float a = b4[t];
#pragma unroll
        for (int k = 0; k < 50; ++k) a += hid4[k] * k4[k * 256 + t];
        lbw0[t] = tanhf(a);
    }
}

// Fused c-coefficients + MFMA einsum + softmax + partial store.
// One block per i (grid 256), 512 threads = 8 waves, 1 block/CU.
__global__ __launch_bounds__(512, 1) void k_mainc(
    const unsigned short* __restrict__ lf,   // (512,64) bf16 bits
    const float* __restrict__ kernel_r,      // (256,64,256) f32
    const float* __restrict__ lfw,           // (256,64)
    const float* __restrict__ kw,            // (256,64,256), j=0 slice
    const float* __restrict__ mem,           // row 0 used
    const float* __restrict__ lbw0,          // (256)
    const float* __restrict__ wsig,          // (65536)
    float* __restrict__ partial) {           // (512,256) [b][i]
    __shared__ __align__(16) unsigned short KrT[256 * 64];  // 32 KB
    __shared__ float cLDS[256];
    __shared__ float wpart[4];
    const int i = blockIdx.x;
    const int tid = threadIdx.x;
    const int lane = tid & 63;
    const int wv = tid >> 6;

    // Stage: transpose + f32->bf16. COALESCED (wave-uniform d, 64 consecutive
    // l = 256 B per load) + PREFETCH-ALL (32 loads in flight per thread).
    // XOR swizzle (byte ^= (l&7)<<4) keeps ds_read_b128 conflict-free;
    // ds_write takes a benign 8-way conflict. (r10/r12-verified)
    {
        const int l = tid & 255;
        const int dh = tid >> 8;
        const float* src = kernel_r + (size_t)i * 16384 + (size_t)dh * 32 * 256 + l;
        float v[32];
#pragma unroll
        for (int j = 0; j < 32; ++j) v[j] = src[(size_t)j * 256];
        char* lds = (char*)KrT;
#pragma unroll
        for (int j = 0; j < 16; ++j) {
            const int d = dh * 32 + 2 * j;
            const unsigned int pk =
                (unsigned int)f2bf(v[2 * j]) | ((unsigned int)f2bf(v[2 * j + 1]) << 16);
            const int byteoff = ((l * 64 + d) * 2) ^ ((l & 7) << 4);
            *(unsigned int*)(lds + byteoff) = pk;
        }
    }

    // c-phase (threads 0..255, one l each) overlaps the staging loads.
    // 4 independent accumulators; logits O(0.04) -> no max-subtraction.
    // c-tail factors prefetched alongside.
    float e_c = 0.f, cf = 0.f;
    if (tid < 256) {
        const int l = tid;
        cf = mem[l] * (1.f + 0.5f * lbw0[l]) * wsig[i * 256 + l];  // prefetch
        float s0 = 0.f, s1 = 0.f, s2 = 0.f, s3 = 0.f;
        const float* lrow = lfw + i * 64;
        const float* kp = kw + l;
#pragma unroll 4
        for (int d = 0; d < 64; d += 4) {
            s0 += lrow[d + 0] * kp[(d + 0) * 256];
            s1 += lrow[d + 1] * kp[(d + 1) * 256];
            s2 += lrow[d + 2] * kp[(d + 2) * 256];
            s3 += lrow[d + 3] * kp[(d + 3) * 256];
        }
        e_c = __expf((s0 + s1) + (s2 + s3));
        float se = e_c;
#pragma unroll
        for (int off = 1; off < 64; off <<= 1) se += __shfl_xor(se, off, 64);
        if (lane == 0) wpart[wv] = se;
    }
    __syncthreads();
    if (tid < 256) {
        const float tot = wpart[0] + wpart[1] + wpart[2] + wpart[3];
        cLDS[tid] = cf * (e_c / tot);
    }
    __syncthreads();

    const int c = lane & 15, g = lane >> 4;

    // A fragments for ALL 4 p-passes hoisted (8 short8 = 32 VGPR): no serial
    // L2 stalls between MFMA passes.
    short8 Af0[4], Af1[4];
#pragma unroll
    for (int p = 0; p < 4; ++p) {
        const int b0 = wv * 64 + p * 16;
        Af0[p] = *(const short8*)(lf + (b0 + c) * 64 + g * 8);
        Af1[p] = *(const short8*)(lf + (b0 + c) * 64 + 32 + g * 8);
    }

    // B fragments: 16 N-tiles x 2 K-halves. B[k][col]: col = lane&15,
    // k = kh*32 + (lane>>4)*8 + j.
    short8 Bf0[16], Bf1[16];
    {
        const char* lds = (const char*)KrT;
#pragma unroll
        for (int n = 0; n < 16; ++n) {
            const int l = n * 16 + c;
            const int base = l * 128 + g * 16;
            Bf0[n] = *(const short8*)(lds + ((base) ^ ((l & 7) << 4)));
            Bf1[n] = *(const short8*)(lds + ((base + 64) ^ ((l & 7) << 4)));
        }
    }
    float ccv[16];
#pragma unroll
    for (int n = 0; n < 16; ++n) ccv[n] = cLDS[n * 16 + c];

#pragma unroll
    for (int p = 0; p < 4; ++p) {
        const int b0 = wv * 64 + p * 16;
        f32x4 acc[16];
#pragma unroll
        for (int n = 0; n < 16; ++n) acc[n] = (f32x4){0.f, 0.f, 0.f, 0.f};
#pragma unroll
        for (int n = 0; n < 16; ++n) {
            acc[n] = __builtin_amdgcn_mfma_f32_16x16x32_bf16(Af0[p], Bf0[n], acc[n], 0, 0, 0);
            acc[n] = __builtin_amdgcn_mfma_f32_16x16x32_bf16(Af1[p], Bf1[n], acc[n], 0, 0, 0);
        }
        // D layout: row = (lane>>4)*4 + r, col = n*16 + (lane&15).
        // Softmax over cols: in-lane over n, then 16-lane xor-reduce.
#pragma unroll
        for (int r = 0; r < 4; ++r) {
            float se = 0.f, sw = 0.f;
#pragma unroll
            for (int n = 0; n < 16; ++n) {
                const float e = __expf(acc[n][r]);
                se += e;
                sw += ccv[n] * e;
            }
#pragma unroll
            for (int off = 1; off < 16; off <<= 1) {
                se += __shfl_xor(se, off, 64);
                sw += __shfl_xor(sw, off, 64);
            }
            if (c == 0) partial[(b0 + g * 4 + r) * 256 + i] = sw / se;
        }
    }
}

// Final reduce: 4 rows per block (grid 128), f32x4 loads + shuffle reduce.
__global__ __launch_bounds__(256) void k_out2(const float* __restrict__ partial,
                                              float* __restrict__ out) {
    const int t = threadIdx.x;
    const int rq = t >> 6, lane = t & 63;
    const int row = blockIdx.x * 4 + rq;
    const f32x4 v = *(const f32x4*)&partial[row * 256 + lane * 4];
    float s = v.x + v.y + v.z + v.w;
#pragma unroll
    for (int off = 1; off < 64; off <<= 1) s += __shfl_xor(s, off, 64);
    if (lane == 0) out[row] = 1.f / (1.f + __expf(-s));
}

extern "C" void kernel_launch(void* const* d_in, const int* in_sizes, int n_in,
                              void* d_out, int out_size, void* d_ws, size_t ws_size,
                              hipStream_t stream) {
    (void)in_sizes; (void)n_in; (void)out_size; (void)ws_size;
    const float* x    = (const float*)d_in[0];
    const float* mem  = (const float*)d_in[1];
    const float* k1   = (const float*)d_in[2];
    const float* b1   = (const float*)d_in[3];
    const float* k20  = (const float*)d_in[4];
    const float* b20  = (const float*)d_in[5];
    const float* k30  = (const float*)d_in[6];
    const float* b30  = (const float*)d_in[7];
    const float* k40  = (const float*)d_in[8];
    const float* b40  = (const float*)d_in[9];
    const float* k2   = (const float*)d_in[10];
    const float* b2   = (const float*)d_in[11];
    const float* k3   = (const float*)d_in[12];
    const float* b3   = (const float*)d_in[13];
    const float* k4   = (const float*)d_in[14];
    const float* b4   = (const float*)d_in[15];
    const float* kr   = (const float*)d_in[16];
    const float* kw   = (const float*)d_in[17];
    const float* wsig = (const float*)d_in[18];
    float* out = (float*)d_out;

    float* ws   = (float*)d_ws;
    float* lfw  = ws;                    // 256*64 f
    float* lbw0 = lfw + 256 * 64;        // 256 f
    float* part = lbw0 + 256;            // 512*256 f
    unsigned short* lf_bf = (unsigned short*)(part + 131072);  // 512*64 bf16

    hipLaunchKernelGGL(k_front, dim3(512), dim3(256), 0, stream, x,
                       k1, b1, k20, b20, k2, b2, k30, b30, k3, b3,
                       k40, b40, k4, b4, lf_bf, lfw, lbw0);
    hipLaunchKernelGGL(k_mainc, dim3(256), dim3(512), 0, stream,
                       lf_bf, kr, lfw, kw, mem, lbw0, wsig, part);
    hipLaunchKernelGGL(k_out2,  dim3(128), dim3(256), 0, stream, part, out);
}